// Round 2
// baseline (2608.466 us; speedup 1.0000x reference)
//
#include <hip/hip_runtime.h>
#include <hip/hip_bf16.h>
#include <math.h>

// Problem constants (from reference setup_inputs)
#define BB 32
#define CIN 128
#define HH 56
#define WW 56
#define COUT 256
#define HW (HH*WW)              // 3136
#define BHW (BB*HW)             // 100352
#define M_ELEMS ((long)BB*COUT*HW)  // 25,690,112
#define PH 28
#define PW 28
#define POOL_ELEMS ((long)BB*COUT*PH*PW) // 6,422,528
#define WELEMS (COUT*CIN*9)     // 294,912

using bf16 = __hip_bfloat16;

// workspace storage-type helpers (float ws if it fits, bf16 ws fallback)
__device__ __forceinline__ float ldv(const float* p, long i){ return p[i]; }
__device__ __forceinline__ float ldv(const bf16*  p, long i){ return __bfloat162float(p[i]); }
__device__ __forceinline__ void  stv(float* p, long i, float v){ p[i]=v; }
__device__ __forceinline__ void  stv(bf16*  p, long i, float v){ p[i]=__float2bfloat16(v); }

// ---------------- kernel 0: weight transpose  w[co][ci][kh][kw] -> wT[r][co], r=ci*9+kh*3+kw
__global__ void wtrans_kernel(const float* __restrict__ w, float* __restrict__ wT){
    int out = blockIdx.x*256 + threadIdx.x;
    if (out >= WELEMS) return;
    int co = out % COUT;
    int r  = out / COUT;
    wT[out] = w[(long)co*(CIN*9) + r];
}

// ---------------- kernel 1: dual conv (mean path + variance path)
// block: 256 threads = one co each; block computes one (b, h, half) -> 28 w positions x 256 co
#define CI_CHUNK 64
#define XW 32   // padded LDS row width (30 used)

template<typename ST>
__global__ __launch_bounds__(256) void conv_kernel(
    const float* __restrict__ mean, const float* __restrict__ stdv,
    const float* __restrict__ wT, const float* __restrict__ bias,
    ST* __restrict__ m_out, ST* __restrict__ v_out)
{
    __shared__ float lds_m[CI_CHUNK][3][XW];
    __shared__ float lds_s[CI_CHUNK][3][XW];
    const int co   = threadIdx.x;
    const int half = blockIdx.x;   // 0..1
    const int h    = blockIdx.y;   // 0..55
    const int b    = blockIdx.z;   // 0..31
    const int w_base = half*28;

    float acc_m[28], acc_v[28];
    #pragma unroll
    for (int i=0;i<28;i++){ acc_m[i]=0.f; acc_v[i]=0.f; }

    for (int c=0; c<CIN; c+=CI_CHUNK){
        // stage input rows h-1..h+1, w_base-1..w_base+28 for this ci chunk
        for (int t = threadIdx.x; t < CI_CHUNK*3*30; t += 256){
            int pos = t % 30; int r = t / 30; int hh = r % 3; int ci_l = r / 3;
            int gh = h - 1 + hh; int gw = w_base - 1 + pos;
            float vm = 0.f, vs = 0.f;
            if ((unsigned)gh < (unsigned)HH && (unsigned)gw < (unsigned)WW){
                long gi = ((long)(b*CIN + (c+ci_l))*HH + gh)*WW + gw;
                vm = mean[gi];
                float sv = stdv[gi];
                vs = sv*sv;
            }
            lds_m[ci_l][hh][pos] = vm;
            lds_s[ci_l][hh][pos] = vs;
        }
        __syncthreads();

        for (int ci_l=0; ci_l<CI_CHUNK; ++ci_l){
            int rbase = (c+ci_l)*9;
            #pragma unroll
            for (int kh=0; kh<3; ++kh){
                float w0 = wT[(long)(rbase + kh*3 + 0)*COUT + co];
                float w1 = wT[(long)(rbase + kh*3 + 1)*COUT + co];
                float w2 = wT[(long)(rbase + kh*3 + 2)*COUT + co];
                {
                    float xm[30];
                    #pragma unroll
                    for (int p=0;p<30;p++) xm[p] = lds_m[ci_l][kh][p];
                    #pragma unroll
                    for (int i=0;i<28;i++) acc_m[i] += w0*xm[i] + w1*xm[i+1] + w2*xm[i+2];
                }
                {
                    float q0=w0*w0, q1=w1*w1, q2=w2*w2;
                    float xs[30];
                    #pragma unroll
                    for (int p=0;p<30;p++) xs[p] = lds_s[ci_l][kh][p];
                    #pragma unroll
                    for (int i=0;i<28;i++) acc_v[i] += q0*xs[i] + q1*xs[i+1] + q2*xs[i+2];
                }
            }
        }
        __syncthreads();
    }

    float bv = bias[co];
    long obase = ((long)(b*COUT+co)*HH + h)*WW + w_base;
    #pragma unroll
    for (int i=0;i<28;i++){
        stv(m_out, obase+i, acc_m[i]+bv);
        stv(v_out, obase+i, acc_v[i]);
    }
}

// ---------------- kernel 2: per-channel mean/inv-std of m over (B,H,W)
template<typename ST>
__global__ void stats_kernel(const ST* __restrict__ m,
                             float* __restrict__ mu_out, float* __restrict__ inv_out){
    int co = blockIdx.x;
    float s=0.f, s2=0.f;
    for (int idx = threadIdx.x; idx < BHW; idx += 256){
        int b = idx / HW, pos = idx % HW;
        float v = ldv(m, ((long)(b*COUT+co))*HW + pos);
        s += v; s2 += v*v;
    }
    __shared__ float rs[256], rs2[256];
    rs[threadIdx.x]=s; rs2[threadIdx.x]=s2; __syncthreads();
    for (int o=128;o>0;o>>=1){
        if (threadIdx.x < o){ rs[threadIdx.x]+=rs[threadIdx.x+o]; rs2[threadIdx.x]+=rs2[threadIdx.x+o]; }
        __syncthreads();
    }
    if (threadIdx.x==0){
        float mu = rs[0]/(float)BHW;
        float var = rs2[0]/(float)BHW - mu*mu;
        mu_out[co] = mu;
        inv_out[co] = 1.0f/sqrtf(var + 1e-5f);
    }
}

// ---------------- kernel 3: BN + erf + 2x2 pool -> f32 outputs
template<typename ST>
__global__ void final_kernel(const ST* __restrict__ m, const ST* __restrict__ var,
                             const float* __restrict__ mu_, const float* __restrict__ inv_,
                             const float* __restrict__ gamma, const float* __restrict__ beta,
                             float* __restrict__ out){
    long idx = (long)blockIdx.x*256 + threadIdx.x;   // < POOL_ELEMS
    int wo = (int)(idx % PW); long t = idx / PW;
    int ho = (int)(t % PH); t /= PH;
    int co = (int)(t % COUT); int b = (int)(t / COUT);
    float g  = gamma[co];
    float be = beta[co];
    float mu = mu_[co], inv = inv_[co];
    float ag = fabsf(g);
    float us = 0.f, ss = 0.f;
    #pragma unroll
    for (int dh=0; dh<2; ++dh){
        int hpos = 2*ho+dh;
        long base = ((long)(b*COUT+co)*HH + hpos)*WW + 2*wo;
        #pragma unroll
        for (int dw=0; dw<2; ++dw){
            float mm = ldv(m,   base+dw);
            float vv = ldv(var, base+dw);
            float sdev = sqrtf(vv + 1e-12f);
            float uhat = (mm - mu)*inv*g + be;
            float shat = sdev*inv*ag;
            float z = uhat / (shat*1.41421356237f + 1e-12f);
            float u = 0.5f*(1.f + erff(z));
            float sa2 = fmaxf(u*(1.f-u), 1e-12f);
            us += u; ss += sa2;
        }
    }
    out[idx]              = 0.25f*us;
    out[POOL_ELEMS + idx] = sqrtf(0.25f*ss)*0.5f;
}

// ---------------- launcher
template<typename ST>
static void run_pipeline(const float* mean, const float* stdv, const float* conv_w,
                         const float* conv_b, const float* gamma, const float* beta,
                         float* out, char* ws, hipStream_t stream)
{
    size_t es = sizeof(ST);
    ST* m_buf = (ST*)ws;
    ST* v_buf = (ST*)(ws + (size_t)M_ELEMS*es);
    float* wT = (float*)(ws + (size_t)M_ELEMS*es*2);
    float* mu = (float*)(ws + (size_t)M_ELEMS*es*2 + (size_t)WELEMS*4);
    float* inv = mu + 256;

    wtrans_kernel<<<WELEMS/256, 256, 0, stream>>>(conv_w, wT);
    conv_kernel<ST><<<dim3(2, HH, BB), 256, 0, stream>>>(mean, stdv, wT, conv_b, m_buf, v_buf);
    stats_kernel<ST><<<COUT, 256, 0, stream>>>(m_buf, mu, inv);
    final_kernel<ST><<<(int)(POOL_ELEMS/256), 256, 0, stream>>>(m_buf, v_buf, mu, inv, gamma, beta, out);
}

extern "C" void kernel_launch(void* const* d_in, const int* in_sizes, int n_in,
                              void* d_out, int out_size, void* d_ws, size_t ws_size,
                              hipStream_t stream)
{
    const float* mean   = (const float*)d_in[0];
    const float* stdv   = (const float*)d_in[1];
    const float* conv_w = (const float*)d_in[2];
    const float* conv_b = (const float*)d_in[3];
    const float* gamma  = (const float*)d_in[4];
    const float* beta   = (const float*)d_in[5];
    float* out = (float*)d_out;
    char* ws = (char*)d_ws;

    const size_t needF = (size_t)M_ELEMS*8 + (size_t)WELEMS*4 + 4096; // f32 m+var
    const size_t needB = (size_t)M_ELEMS*4 + (size_t)WELEMS*4 + 4096; // bf16 m+var

    if (ws_size >= needF){
        run_pipeline<float>(mean, stdv, conv_w, conv_b, gamma, beta, out, ws, stream);
    } else if (ws_size >= needB){
        run_pipeline<bf16>(mean, stdv, conv_w, conv_b, gamma, beta, out, ws, stream);
    }
    // else: insufficient workspace — validation will fail visibly (absmax=1.0),
    // signalling we must switch to a recompute (ws-free) strategy.
}

// Round 3
// 319.894 us; speedup vs baseline: 8.1542x; 8.1542x over previous
//
#include <hip/hip_runtime.h>
#include <hip/hip_bf16.h>
#include <math.h>

// ---------------- problem constants ----------------
#define BB 32
#define CIN 128
#define HH 56
#define WW 56
#define COUT 256
#define HW (HH*WW)              // 3136
#define NPIX (BB*HW)            // 100352
#define PH 28
#define PW 28
#define POOL_ELEMS ((long)BB*COUT*PH*PW) // 6,422,528
#define PADH 58
#define PADW 58

typedef unsigned short u16;
using s16x8 = __attribute__((ext_vector_type(8))) short;
using s16x4 = __attribute__((ext_vector_type(4))) short;
using f32x4 = __attribute__((ext_vector_type(4))) float;

__device__ __forceinline__ float b2f(u16 u){ return __uint_as_float(((unsigned)u)<<16); }
__device__ __forceinline__ u16 f2b(float x){           // RNE f32->bf16 (no NaN inputs here)
    unsigned u = __float_as_uint(x);
    unsigned r = (u + 0x7fffu + ((u>>16)&1u)) >> 16;
    return (u16)r;
}

__device__ __forceinline__ void gload16(const void* g, void* l){
    __builtin_amdgcn_global_load_lds(
        (const __attribute__((address_space(1))) unsigned int*)g,
        (__attribute__((address_space(3))) unsigned int*)l, 16, 0, 0);
}

// ================= FAST PATH =================

// kernel F0: NCHW f32 -> padded NHWC bf16 (mean, std^2). Pad border pre-zeroed by memset.
__global__ __launch_bounds__(256) void transform_kernel(
    const float* __restrict__ mean, const float* __restrict__ stdv,
    u16* __restrict__ mean_pad, u16* __restrict__ std2_pad)
{
    int t   = blockIdx.x*256 + threadIdx.x;   // exactly BB*HH*WW*16 threads
    int oct = t & 15;
    int pix = t >> 4;
    int w = pix % WW; int tmp = pix / WW;
    int h = tmp % HH; int b = tmp / HH;
    long ibase = ((long)(b*CIN + oct*8)*HH + h)*WW + w;
    s16x8 pm, ps;
    #pragma unroll
    for (int j=0;j<8;j++){
        float m = mean[ibase + (long)j*HW];
        float s = stdv[ibase + (long)j*HW];
        pm[j] = (short)f2b(m);
        ps[j] = (short)f2b(s*s);
    }
    size_t obase = (((size_t)b*PADH + (h+1))*PADW + (w+1))*CIN + oct*8;
    *(s16x8*)(mean_pad + obase) = pm;
    *(s16x8*)(std2_pad + obase) = ps;
}

// kernel F1: w[co][ci][3][3] f32 -> wT[r][co][ci] bf16 and squared copy
__global__ __launch_bounds__(256) void wtransb_kernel(
    const float* __restrict__ w, u16* __restrict__ wT, u16* __restrict__ wT2)
{
    int t = blockIdx.x*256 + threadIdx.x;   // exactly 294912
    int ci = t & 127;
    int co = (t>>7) & 255;
    int r  = t >> 15;                        // 0..8
    float v = w[((long)co*CIN + ci)*9 + r];
    long o = ((long)r*COUT + co)*CIN + ci;
    wT[o]  = f2b(v);
    wT2[o] = f2b(v*v);
}

// kernel F2: dual implicit-GEMM conv via MFMA.
// Tiles: BM=128 pixels, BN=128 co, BK=32 ci; outer loop over 9 (kh,kw).
// 4 waves (2x2), each wave 64x64, 4x4 frags of 16x16x32, dual accumulators.
__global__ __launch_bounds__(256,2) void convmma_kernel(
    const u16* __restrict__ mean_pad, const u16* __restrict__ std2_pad,
    const u16* __restrict__ wT, const u16* __restrict__ wT2,
    const float* __restrict__ bias,
    u16* __restrict__ m_out, u16* __restrict__ v_out)
{
    __shared__ u16 lds[4][4096];   // Am, Av, Bm, Bv : each [128 rows][32 ci] bf16 = 8KB
    const int tid  = threadIdx.x;
    const int lane = tid & 63;
    const int wid  = tid >> 6;
    const int wm   = wid >> 1, wn = wid & 1;

    // XCD-bijective swizzle: 1568 blocks, 1568/8 = 196
    int bid = blockIdx.x;
    int swz = (bid & 7) * 196 + (bid >> 3);
    const int pix0 = (swz >> 1) * 128;
    const int co0  = (swz & 1) * 128;

    // ---- staging precompute (per thread). slot s = i*256+tid; row = s>>2; q = tid&3.
    // LDS is written LINEARLY by global_load_lds; the ci-quadrant is pre-swizzled on
    // the GLOBAL source (q ^ ((row>>1)&3)) and the same XOR is applied on ds_read.
    const int q = tid & 3;
    size_t aoff[2], boff[2];
    #pragma unroll
    for (int i=0;i<2;i++){
        int apix = i*64 + (tid>>2);
        int gp = pix0 + apix;
        int b = gp / HW; int rem = gp % HW;
        int h = rem / WW; int w = rem % WW;
        aoff[i] = (((size_t)b*PADH + h)*PADW + w)*CIN + (size_t)((q ^ ((apix>>1)&3))*8);
        int bco = i*64 + (tid>>2);
        boff[i] = ((size_t)(co0 + bco))*CIN + (size_t)((q ^ ((bco>>1)&3))*8);
    }
    const int ldst0 = (wid*64)*8;           // u16 index of this wave's slice, issue 0
    const int ldst1 = (256 + wid*64)*8;     // issue 1

    // ---- fragment read offsets (u16 index inside a [128][32] tile)
    int a_idx[4], b_idx[4];
    #pragma unroll
    for (int t4=0;t4<4;t4++){
        int row  = wm*64 + t4*16 + (lane & 15);
        a_idx[t4] = row*32  + (((lane>>4) ^ ((row>>1)&3))*8);
        int crow = wn*64 + t4*16 + (lane & 15);
        b_idx[t4] = crow*32 + (((lane>>4) ^ ((crow>>1)&3))*8);
    }

    f32x4 accm[4][4], accv[4][4];
    #pragma unroll
    for (int i=0;i<4;i++)
      #pragma unroll
      for (int j=0;j<4;j++){
          accm[i][j] = (f32x4){0.f,0.f,0.f,0.f};
          accv[i][j] = (f32x4){0.f,0.f,0.f,0.f};
      }

    for (int r=0; r<9; ++r){
        const int kh = r/3, kw = r - kh*3;
        const size_t ash = (size_t)(kh*PADW + kw)*CIN;
        const size_t wsh = (size_t)r*COUT*CIN;
        for (int cs=0; cs<4; ++cs){
            const size_t ao = ash + (size_t)cs*32;
            const size_t wo = wsh + (size_t)cs*32;
            __syncthreads();   // all waves done reading LDS from previous step
            gload16(mean_pad + aoff[0] + ao, &lds[0][ldst0]);
            gload16(mean_pad + aoff[1] + ao, &lds[0][ldst1]);
            gload16(std2_pad + aoff[0] + ao, &lds[1][ldst0]);
            gload16(std2_pad + aoff[1] + ao, &lds[1][ldst1]);
            gload16(wT  + boff[0] + wo, &lds[2][ldst0]);
            gload16(wT  + boff[1] + wo, &lds[2][ldst1]);
            gload16(wT2 + boff[0] + wo, &lds[3][ldst0]);
            gload16(wT2 + boff[1] + wo, &lds[3][ldst1]);
            __syncthreads();   // compiler drains vmcnt(0) before s_barrier -> LDS ready

            s16x8 af[4], bfg[4];
            #pragma unroll
            for (int t4=0;t4<4;t4++) af[t4]  = *(const s16x8*)&lds[0][a_idx[t4]];
            #pragma unroll
            for (int t4=0;t4<4;t4++) bfg[t4] = *(const s16x8*)&lds[2][b_idx[t4]];
            #pragma unroll
            for (int mi=0;mi<4;mi++)
              #pragma unroll
              for (int ni=0;ni<4;ni++)
                accm[mi][ni] = __builtin_amdgcn_mfma_f32_16x16x32_bf16(af[mi], bfg[ni], accm[mi][ni], 0,0,0);
            #pragma unroll
            for (int t4=0;t4<4;t4++) af[t4]  = *(const s16x8*)&lds[1][a_idx[t4]];
            #pragma unroll
            for (int t4=0;t4<4;t4++) bfg[t4] = *(const s16x8*)&lds[3][b_idx[t4]];
            #pragma unroll
            for (int mi=0;mi<4;mi++)
              #pragma unroll
              for (int ni=0;ni<4;ni++)
                accv[mi][ni] = __builtin_amdgcn_mfma_f32_16x16x32_bf16(af[mi], bfg[ni], accv[mi][ni], 0,0,0);
        }
    }

    // ---- epilogue: bias + bf16 store (NCHW). D-frag: col=lane&15, row=(lane>>4)*4+reg.
    float bv[4];
    #pragma unroll
    for (int ni=0;ni<4;ni++) bv[ni] = bias[co0 + wn*64 + ni*16 + (lane&15)];

    #pragma unroll
    for (int mi=0;mi<4;mi++){
        int pixl = wm*64 + mi*16 + ((lane>>4)<<2);
        int gp = pix0 + pixl;
        int b = gp / HW; int hw = gp - b*HW;   // 4 consecutive pix stay in same (b,h-row)
        #pragma unroll
        for (int ni=0;ni<4;ni++){
            int co = co0 + wn*64 + ni*16 + (lane&15);
            size_t o = (size_t)(b*COUT + co)*HW + hw;
            s16x4 pm, pv;
            #pragma unroll
            for (int rr=0;rr<4;rr++){
                pm[rr] = (short)f2b(accm[mi][ni][rr] + bv[ni]);
                pv[rr] = (short)f2b(accv[mi][ni][rr]);
            }
            *(s16x4*)(m_out + o) = pm;
            *(s16x4*)(v_out + o) = pv;
        }
    }
}

// ================= SHARED TAIL (both paths) =================

// per-channel mean / inv-std of m over (B,H,W); m is bf16 NCHW
__global__ __launch_bounds__(256) void stats_kernel(const u16* __restrict__ m,
        float* __restrict__ mu_out, float* __restrict__ inv_out){
    int co = blockIdx.x;
    float s=0.f, s2=0.f;
    for (int oc = threadIdx.x; oc < NPIX/8; oc += 256){
        int b = oc / (HW/8); int o8 = oc - b*(HW/8);
        const s16x8 v8 = *(const s16x8*)&m[((size_t)(b*COUT+co))*HW + (size_t)o8*8];
        #pragma unroll
        for (int j=0;j<8;j++){ float v = b2f((u16)v8[j]); s += v; s2 += v*v; }
    }
    __shared__ float rs[256], rs2[256];
    rs[threadIdx.x]=s; rs2[threadIdx.x]=s2; __syncthreads();
    for (int o=128;o>0;o>>=1){
        if (threadIdx.x < o){ rs[threadIdx.x]+=rs[threadIdx.x+o]; rs2[threadIdx.x]+=rs2[threadIdx.x+o]; }
        __syncthreads();
    }
    if (threadIdx.x==0){
        float mu = rs[0]/(float)NPIX;
        float var = rs2[0]/(float)NPIX - mu*mu;
        mu_out[co] = mu;
        inv_out[co] = 1.0f/sqrtf(var + 1e-5f);
    }
}

// BN + erf + 2x2 pool -> f32 outputs
__global__ __launch_bounds__(256) void final_kernel(
        const u16* __restrict__ m, const u16* __restrict__ var,
        const float* __restrict__ mu_, const float* __restrict__ inv_,
        const float* __restrict__ gamma, const float* __restrict__ beta,
        float* __restrict__ out){
    long idx = (long)blockIdx.x*256 + threadIdx.x;   // < POOL_ELEMS
    int wo = (int)(idx % PW); long t = idx / PW;
    int ho = (int)(t % PH); t /= PH;
    int co = (int)(t % COUT); int b = (int)(t / COUT);
    float g  = gamma[co];
    float be = beta[co];
    float mu = mu_[co], inv = inv_[co];
    float ag = fabsf(g);
    float us = 0.f, ss = 0.f;
    #pragma unroll
    for (int dh=0; dh<2; ++dh){
        int hpos = 2*ho+dh;
        long base = ((long)(b*COUT+co)*HH + hpos)*WW + 2*wo;
        #pragma unroll
        for (int dw=0; dw<2; ++dw){
            float mm = b2f(m[base+dw]);
            float vv = b2f(var[base+dw]);
            float sdev = sqrtf(vv + 1e-12f);
            float uhat = (mm - mu)*inv*g + be;
            float shat = sdev*inv*ag;
            float z = uhat / (shat*1.41421356237f + 1e-12f);
            float u = 0.5f*(1.f + erff(z));
            float sa2 = fmaxf(u*(1.f-u), 1e-12f);
            us += u; ss += sa2;
        }
    }
    out[idx]              = 0.25f*us;
    out[POOL_ELEMS + idx] = sqrtf(0.25f*ss)*0.5f;
}

// ================= FALLBACK PATH (round-2 VALU conv, bf16 m/v out) =================

__global__ void wtransf_kernel(const float* __restrict__ w, float* __restrict__ wT){
    int out = blockIdx.x*256 + threadIdx.x;
    if (out >= COUT*CIN*9) return;
    int co = out % COUT;
    int r  = out / COUT;
    wT[out] = w[(long)co*(CIN*9) + r];
}

#define CI_CHUNK 64
#define XW 32
__global__ __launch_bounds__(256) void conv_old_kernel(
    const float* __restrict__ mean, const float* __restrict__ stdv,
    const float* __restrict__ wT, const float* __restrict__ bias,
    u16* __restrict__ m_out, u16* __restrict__ v_out)
{
    __shared__ float lds_m[CI_CHUNK][3][XW];
    __shared__ float lds_s[CI_CHUNK][3][XW];
    const int co   = threadIdx.x;
    const int half = blockIdx.x;
    const int h    = blockIdx.y;
    const int b    = blockIdx.z;
    const int w_base = half*28;

    float acc_m[28], acc_v[28];
    #pragma unroll
    for (int i=0;i<28;i++){ acc_m[i]=0.f; acc_v[i]=0.f; }

    for (int c=0; c<CIN; c+=CI_CHUNK){
        for (int t = threadIdx.x; t < CI_CHUNK*3*30; t += 256){
            int pos = t % 30; int r = t / 30; int hh = r % 3; int ci_l = r / 3;
            int gh = h - 1 + hh; int gw = w_base - 1 + pos;
            float vm = 0.f, vs = 0.f;
            if ((unsigned)gh < (unsigned)HH && (unsigned)gw < (unsigned)WW){
                long gi = ((long)(b*CIN + (c+ci_l))*HH + gh)*WW + gw;
                vm = mean[gi];
                float sv = stdv[gi];
                vs = sv*sv;
            }
            lds_m[ci_l][hh][pos] = vm;
            lds_s[ci_l][hh][pos] = vs;
        }
        __syncthreads();
        for (int ci_l=0; ci_l<CI_CHUNK; ++ci_l){
            int rbase = (c+ci_l)*9;
            #pragma unroll
            for (int kh=0; kh<3; ++kh){
                float w0 = wT[(long)(rbase + kh*3 + 0)*COUT + co];
                float w1 = wT[(long)(rbase + kh*3 + 1)*COUT + co];
                float w2 = wT[(long)(rbase + kh*3 + 2)*COUT + co];
                float xm[30];
                #pragma unroll
                for (int p=0;p<30;p++) xm[p] = lds_m[ci_l][kh][p];
                #pragma unroll
                for (int i=0;i<28;i++) acc_m[i] += w0*xm[i] + w1*xm[i+1] + w2*xm[i+2];
                float q0=w0*w0, q1=w1*w1, q2=w2*w2;
                float xs[30];
                #pragma unroll
                for (int p=0;p<30;p++) xs[p] = lds_s[ci_l][kh][p];
                #pragma unroll
                for (int i=0;i<28;i++) acc_v[i] += q0*xs[i] + q1*xs[i+1] + q2*xs[i+2];
            }
        }
        __syncthreads();
    }
    float bvv = bias[co];
    long obase = ((long)(b*COUT+co)*HH + h)*WW + w_base;
    #pragma unroll
    for (int i=0;i<28;i++){
        m_out[obase+i] = f2b(acc_m[i]+bvv);
        v_out[obase+i] = f2b(acc_v[i]);
    }
}

// ================= launcher =================
extern "C" void kernel_launch(void* const* d_in, const int* in_sizes, int n_in,
                              void* d_out, int out_size, void* d_ws, size_t ws_size,
                              hipStream_t stream)
{
    const float* mean   = (const float*)d_in[0];
    const float* stdv   = (const float*)d_in[1];
    const float* conv_w = (const float*)d_in[2];
    const float* conv_b = (const float*)d_in[3];
    const float* gamma  = (const float*)d_in[4];
    const float* beta   = (const float*)d_in[5];
    float* out = (float*)d_out;
    char* ws = (char*)d_ws;

    // fast-path workspace layout (bytes)
    const size_t PAD_BYTES  = (size_t)BB*PADH*PADW*CIN*2;        // 27,549,696
    const size_t OFF_STD2   = PAD_BYTES;
    const size_t OFF_WT     = 2*PAD_BYTES;                        // 55,099,392
    const size_t WT_BYTES   = (size_t)9*COUT*CIN*2;               // 589,824
    const size_t OFF_WT2    = OFF_WT + WT_BYTES;
    const size_t OFF_M      = OFF_WT2 + WT_BYTES;                 // 56,279,040
    const size_t MV_BYTES   = (size_t)NPIX*COUT/ ( (size_t)1 ) * 0 + (size_t)BB*COUT*HW*2; // 51,380,224
    const size_t OFF_V      = OFF_M + MV_BYTES;
    const size_t OFF_MU     = OFF_V + MV_BYTES;                   // 159,039,488
    const size_t OFF_INV    = OFF_MU + 1024;
    const size_t NEED_FAST  = OFF_INV + 1024;

    if (ws_size >= NEED_FAST){
        u16* mean_pad = (u16*)ws;
        u16* std2_pad = (u16*)(ws + OFF_STD2);
        u16* wT   = (u16*)(ws + OFF_WT);
        u16* wT2  = (u16*)(ws + OFF_WT2);
        u16* m_buf = (u16*)(ws + OFF_M);
        u16* v_buf = (u16*)(ws + OFF_V);
        float* mu  = (float*)(ws + OFF_MU);
        float* inv = (float*)(ws + OFF_INV);

        hipMemsetAsync(ws, 0, 2*PAD_BYTES, stream);   // zero pad halos
        transform_kernel<<<(BB*HH*WW*16)/256, 256, 0, stream>>>(mean, stdv, mean_pad, std2_pad);
        wtransb_kernel<<<(9*COUT*CIN)/256, 256, 0, stream>>>(conv_w, wT, wT2);
        convmma_kernel<<<(NPIX/128)*(COUT/128), 256, 0, stream>>>(
            mean_pad, std2_pad, wT, wT2, conv_b, m_buf, v_buf);
        stats_kernel<<<COUT, 256, 0, stream>>>(m_buf, mu, inv);
        final_kernel<<<(int)(POOL_ELEMS/256), 256, 0, stream>>>(m_buf, v_buf, mu, inv, gamma, beta, out);
    } else {
        // fallback: round-2 structure with bf16 m/v
        u16* m_buf = (u16*)ws;
        u16* v_buf = (u16*)(ws + (size_t)BB*COUT*HW*2);
        float* wT  = (float*)(ws + (size_t)BB*COUT*HW*4);
        float* mu  = (float*)(ws + (size_t)BB*COUT*HW*4 + (size_t)COUT*CIN*9*4);
        float* inv = mu + 256;
        wtransf_kernel<<<(COUT*CIN*9+255)/256, 256, 0, stream>>>(conv_w, wT);
        conv_old_kernel<<<dim3(2, HH, BB), 256, 0, stream>>>(mean, stdv, wT, conv_b, m_buf, v_buf);
        stats_kernel<<<COUT, 256, 0, stream>>>(m_buf, mu, inv);
        final_kernel<<<(int)(POOL_ELEMS/256), 256, 0, stream>>>(m_buf, v_buf, mu, inv, gamma, beta, out);
    }
}

// Round 4
// 280.802 us; speedup vs baseline: 9.2893x; 1.1392x over previous
//
#include <hip/hip_runtime.h>
#include <hip/hip_bf16.h>
#include <math.h>

// ---------------- problem constants ----------------
#define BB 32
#define CIN 128
#define HH 56
#define WW 56
#define COUT 256
#define HW (HH*WW)              // 3136
#define NPIX (BB*HW)            // 100352
#define PH 28
#define PW 28
#define POOL_ELEMS ((long)BB*COUT*PH*PW) // 6,422,528
#define PADH 58
#define PADW 58

typedef unsigned short u16;
using s16x8 = __attribute__((ext_vector_type(8))) short;
using s16x4 = __attribute__((ext_vector_type(4))) short;
using f32x4 = __attribute__((ext_vector_type(4))) float;

__device__ __forceinline__ float b2f(u16 u){ return __uint_as_float(((unsigned)u)<<16); }
__device__ __forceinline__ u16 f2b(float x){           // RNE f32->bf16
    unsigned u = __float_as_uint(x);
    unsigned r = (u + 0x7fffu + ((u>>16)&1u)) >> 16;
    return (u16)r;
}

__device__ __forceinline__ void gload16(const void* g, void* l){
    __builtin_amdgcn_global_load_lds(
        (const __attribute__((address_space(1))) unsigned int*)g,
        (__attribute__((address_space(3))) unsigned int*)l, 16, 0, 0);
}

// ================= FAST PATH =================

// zero the 1-px halo ring of both padded buffers (3.7 MB instead of 55 MB memset)
__global__ __launch_bounds__(256) void halo_kernel(u16* __restrict__ mean_pad,
                                                   u16* __restrict__ std2_pad){
    int t = blockIdx.x*256 + threadIdx.x;     // 32*228*16 threads
    int oct = t & 15;
    int e   = (t >> 4) % 228;
    int b   = (t >> 4) / 228;
    int h, w;
    if (e < 58)       { h = 0;        w = e; }
    else if (e < 116) { h = 57;       w = e - 58; }
    else if (e < 172) { h = e - 115;  w = 0; }       // 1..56
    else              { h = e - 171;  w = 57; }      // 1..56
    size_t o = (((size_t)b*PADH + h)*PADW + w)*CIN + oct*8;
    s16x8 z = (s16x8){0,0,0,0,0,0,0,0};
    *(s16x8*)(mean_pad + o) = z;
    *(s16x8*)(std2_pad + o) = z;
}

// NCHW f32 -> padded NHWC bf16 (mean, std^2)
__global__ __launch_bounds__(256) void transform_kernel(
    const float* __restrict__ mean, const float* __restrict__ stdv,
    u16* __restrict__ mean_pad, u16* __restrict__ std2_pad)
{
    int t   = blockIdx.x*256 + threadIdx.x;   // exactly BB*HH*WW*16 threads
    int oct = t & 15;
    int pix = t >> 4;
    int w = pix % WW; int tmp = pix / WW;
    int h = tmp % HH; int b = tmp / HH;
    long ibase = ((long)(b*CIN + oct*8)*HH + h)*WW + w;
    s16x8 pm, ps;
    #pragma unroll
    for (int j=0;j<8;j++){
        float m = mean[ibase + (long)j*HW];
        float s = stdv[ibase + (long)j*HW];
        pm[j] = (short)f2b(m);
        ps[j] = (short)f2b(s*s);
    }
    size_t obase = (((size_t)b*PADH + (h+1))*PADW + (w+1))*CIN + oct*8;
    *(s16x8*)(mean_pad + obase) = pm;
    *(s16x8*)(std2_pad + obase) = ps;
}

// w[co][ci][3][3] f32 -> wT[r][co][ci] bf16 and squared copy
__global__ __launch_bounds__(256) void wtransb_kernel(
    const float* __restrict__ w, u16* __restrict__ wT, u16* __restrict__ wT2)
{
    int t = blockIdx.x*256 + threadIdx.x;   // exactly 294912
    int ci = t & 127;
    int co = (t>>7) & 255;
    int r  = t >> 15;                        // 0..8
    float v = w[((long)co*CIN + ci)*9 + r];
    long o = ((long)r*COUT + co)*CIN + ci;
    wT[o]  = f2b(v);
    wT2[o] = f2b(v*v);
}

// implicit-GEMM conv via MFMA, SINGLE accumulator per block.
// blockIdx.z: 0 = mean*w (+bias, +BN-stats atomics), 1 = std2*w2.
// Tiles: BM=128 pixels, BN=128 co, BK=32 ci; outer loop over 9 (kh,kw).
// 4 waves (2x2), each wave 64x64, 4x4 frags of 16x16x32.
__global__ __launch_bounds__(256,3) void convs_kernel(
    const u16* __restrict__ mean_pad, const u16* __restrict__ std2_pad,
    const u16* __restrict__ wT, const u16* __restrict__ wT2,
    const float* __restrict__ bias,
    u16* __restrict__ m_out, u16* __restrict__ v_out,
    float* __restrict__ sum_, float* __restrict__ sumsq_)
{
    __shared__ u16 ldsA[4096];   // [128 rows][32 ci] bf16, ci-quadrant XOR-swizzled
    __shared__ u16 ldsB[4096];
    const int tid  = threadIdx.x;
    const int lane = tid & 63;
    const int wid  = tid >> 6;
    const int wm   = wid >> 1, wn = wid & 1;
    const int path = blockIdx.z;

    const u16* __restrict__ Ap = path ? std2_pad : mean_pad;
    const u16* __restrict__ Bp = path ? wT2      : wT;
    u16*       __restrict__ Op = path ? v_out    : m_out;

    // XCD-bijective swizzle: 1568 blocks in x, 1568/8 = 196
    int bid = blockIdx.x;
    int swz = (bid & 7) * 196 + (bid >> 3);
    const int pix0 = (swz >> 1) * 128;
    const int co0  = (swz & 1) * 128;

    // staging: slot s = i*256+tid covers (row = s>>2, q = tid&3); LDS written linearly,
    // ci-quadrant pre-swizzled on the GLOBAL source with q ^ ((row>>1)&3).
    const int q = tid & 3;
    size_t aoff[2], boff[2];
    #pragma unroll
    for (int i=0;i<2;i++){
        int arow = i*64 + (tid>>2);
        int gp = pix0 + arow;
        int b = gp / HW; int rem = gp % HW;
        int h = rem / WW; int w = rem % WW;
        aoff[i] = (((size_t)b*PADH + h)*PADW + w)*CIN + (size_t)((q ^ ((arow>>1)&3))*8);
        boff[i] = ((size_t)(co0 + arow))*CIN + (size_t)((q ^ ((arow>>1)&3))*8);
    }
    const int ldst0 = (wid*64)*8;          // wave-uniform LDS dest, issue 0
    const int ldst1 = (256 + wid*64)*8;    // issue 1

    // fragment read offsets (u16 index in [128][32] tile), same XOR on read
    int a_idx[4], b_idx[4];
    #pragma unroll
    for (int t4=0;t4<4;t4++){
        int row  = wm*64 + t4*16 + (lane & 15);
        a_idx[t4] = row*32  + (((lane>>4) ^ ((row>>1)&3))*8);
        int crow = wn*64 + t4*16 + (lane & 15);
        b_idx[t4] = crow*32 + (((lane>>4) ^ ((crow>>1)&3))*8);
    }

    f32x4 acc[4][4];
    #pragma unroll
    for (int i=0;i<4;i++)
      #pragma unroll
      for (int j=0;j<4;j++) acc[i][j] = (f32x4){0.f,0.f,0.f,0.f};

    for (int r=0; r<9; ++r){
        const size_t ash = (size_t)((r/3)*PADW + (r%3))*CIN;
        const size_t wsh = (size_t)r*COUT*CIN;
        for (int cs=0; cs<4; ++cs){
            const size_t ao = ash + (size_t)cs*32;
            const size_t wo = wsh + (size_t)cs*32;
            __syncthreads();
            gload16(Ap + aoff[0] + ao, &ldsA[ldst0]);
            gload16(Ap + aoff[1] + ao, &ldsA[ldst1]);
            gload16(Bp + boff[0] + wo, &ldsB[ldst0]);
            gload16(Bp + boff[1] + wo, &ldsB[ldst1]);
            __syncthreads();

            s16x8 af[4], bfg[4];
            #pragma unroll
            for (int t4=0;t4<4;t4++) af[t4]  = *(const s16x8*)&ldsA[a_idx[t4]];
            #pragma unroll
            for (int t4=0;t4<4;t4++) bfg[t4] = *(const s16x8*)&ldsB[b_idx[t4]];
            #pragma unroll
            for (int mi=0;mi<4;mi++)
              #pragma unroll
              for (int ni=0;ni<4;ni++)
                acc[mi][ni] = __builtin_amdgcn_mfma_f32_16x16x32_bf16(af[mi], bfg[ni], acc[mi][ni], 0,0,0);
        }
    }

    // epilogue. D-frag: col=lane&15, row=(lane>>4)*4+reg.
    float bv[4];
    if (path == 0){
        #pragma unroll
        for (int ni=0;ni<4;ni++) bv[ni] = bias[co0 + wn*64 + ni*16 + (lane&15)];
    } else {
        #pragma unroll
        for (int ni=0;ni<4;ni++) bv[ni] = 0.f;
    }

    float ssum[4], ssq[4];
    #pragma unroll
    for (int ni=0;ni<4;ni++){ ssum[ni]=0.f; ssq[ni]=0.f; }

    #pragma unroll
    for (int mi=0;mi<4;mi++){
        int pixl = wm*64 + mi*16 + ((lane>>4)<<2);
        int gp = pix0 + pixl;
        int b = gp / HW; int hw = gp - b*HW;   // 4 consecutive pix stay in same (b,h) row
        #pragma unroll
        for (int ni=0;ni<4;ni++){
            int co = co0 + wn*64 + ni*16 + (lane&15);
            size_t o = (size_t)(b*COUT + co)*HW + hw;
            s16x4 pk;
            #pragma unroll
            for (int rr=0;rr<4;rr++){
                float v = acc[mi][ni][rr] + bv[ni];
                pk[rr] = (short)f2b(v);
                ssum[ni] += v;
                ssq[ni]  += v*v;
            }
            *(s16x4*)(Op + o) = pk;
        }
    }

    if (path == 0){
        // reduce over the 4 lane-groups that share (lane&15) => per-co partials
        #pragma unroll
        for (int ni=0;ni<4;ni++){
            float s = ssum[ni], s2 = ssq[ni];
            s  += __shfl_xor(s, 16, 64);  s2 += __shfl_xor(s2, 16, 64);
            s  += __shfl_xor(s, 32, 64);  s2 += __shfl_xor(s2, 32, 64);
            if (lane < 16){
                int co = co0 + wn*64 + ni*16 + lane;
                atomicAdd(&sum_[co],   s);
                atomicAdd(&sumsq_[co], s2);
            }
        }
    }
}

// 1 block: per-channel mu / inv-std from atomic partials
__global__ __launch_bounds__(256) void finalize_kernel(
    const float* __restrict__ sum_, const float* __restrict__ sumsq_,
    float* __restrict__ mu_out, float* __restrict__ inv_out)
{
    int co = threadIdx.x;
    float mu = sum_[co] / (float)NPIX;
    float var = sumsq_[co] / (float)NPIX - mu*mu;
    mu_out[co] = mu;
    inv_out[co] = 1.0f/sqrtf(var + 1e-5f);
}

// BN + erf + 2x2 pool -> f32 outputs
__global__ __launch_bounds__(256) void final_kernel(
        const u16* __restrict__ m, const u16* __restrict__ var,
        const float* __restrict__ mu_, const float* __restrict__ inv_,
        const float* __restrict__ gamma, const float* __restrict__ beta,
        float* __restrict__ out){
    long idx = (long)blockIdx.x*256 + threadIdx.x;   // < POOL_ELEMS
    int wo = (int)(idx % PW); long t = idx / PW;
    int ho = (int)(t % PH); t /= PH;
    int co = (int)(t % COUT); int b = (int)(t / COUT);
    float g  = gamma[co];
    float be = beta[co];
    float mu = mu_[co], inv = inv_[co];
    float ag = fabsf(g);
    float us = 0.f, ss = 0.f;
    #pragma unroll
    for (int dh=0; dh<2; ++dh){
        int hpos = 2*ho+dh;
        long base = ((long)(b*COUT+co)*HH + hpos)*WW + 2*wo;
        #pragma unroll
        for (int dw=0; dw<2; ++dw){
            float mm = b2f(m[base+dw]);
            float vv = b2f(var[base+dw]);
            float sdev = sqrtf(vv + 1e-12f);
            float uhat = (mm - mu)*inv*g + be;
            float shat = sdev*inv*ag;
            float z = uhat / (shat*1.41421356237f + 1e-12f);
            float u = 0.5f*(1.f + erff(z));
            float sa2 = fmaxf(u*(1.f-u), 1e-12f);
            us += u; ss += sa2;
        }
    }
    out[idx]              = 0.25f*us;
    out[POOL_ELEMS + idx] = sqrtf(0.25f*ss)*0.5f;
}

// ================= FALLBACK PATH (round-2 VALU conv, bf16 m/v out) =================

__global__ void wtransf_kernel(const float* __restrict__ w, float* __restrict__ wT){
    int out = blockIdx.x*256 + threadIdx.x;
    if (out >= COUT*CIN*9) return;
    int co = out % COUT;
    int r  = out / COUT;
    wT[out] = w[(long)co*(CIN*9) + r];
}

__global__ __launch_bounds__(256) void stats_old_kernel(const u16* __restrict__ m,
        float* __restrict__ mu_out, float* __restrict__ inv_out){
    int co = blockIdx.x;
    float s=0.f, s2=0.f;
    for (int oc = threadIdx.x; oc < NPIX/8; oc += 256){
        int b = oc / (HW/8); int o8 = oc - b*(HW/8);
        const s16x8 v8 = *(const s16x8*)&m[((size_t)(b*COUT+co))*HW + (size_t)o8*8];
        #pragma unroll
        for (int j=0;j<8;j++){ float v = b2f((u16)v8[j]); s += v; s2 += v*v; }
    }
    __shared__ float rs[256], rs2[256];
    rs[threadIdx.x]=s; rs2[threadIdx.x]=s2; __syncthreads();
    for (int o=128;o>0;o>>=1){
        if (threadIdx.x < o){ rs[threadIdx.x]+=rs[threadIdx.x+o]; rs2[threadIdx.x]+=rs2[threadIdx.x+o]; }
        __syncthreads();
    }
    if (threadIdx.x==0){
        float mu = rs[0]/(float)NPIX;
        float var = rs2[0]/(float)NPIX - mu*mu;
        mu_out[co] = mu;
        inv_out[co] = 1.0f/sqrtf(var + 1e-5f);
    }
}

#define CI_CHUNK 64
#define XW 32
__global__ __launch_bounds__(256) void conv_old_kernel(
    const float* __restrict__ mean, const float* __restrict__ stdv,
    const float* __restrict__ wT, const float* __restrict__ bias,
    u16* __restrict__ m_out, u16* __restrict__ v_out)
{
    __shared__ float lds_m[CI_CHUNK][3][XW];
    __shared__ float lds_s[CI_CHUNK][3][XW];
    const int co   = threadIdx.x;
    const int half = blockIdx.x;
    const int h    = blockIdx.y;
    const int b    = blockIdx.z;
    const int w_base = half*28;

    float acc_m[28], acc_v[28];
    #pragma unroll
    for (int i=0;i<28;i++){ acc_m[i]=0.f; acc_v[i]=0.f; }

    for (int c=0; c<CIN; c+=CI_CHUNK){
        for (int t = threadIdx.x; t < CI_CHUNK*3*30; t += 256){
            int pos = t % 30; int r = t / 30; int hh = r % 3; int ci_l = r / 3;
            int gh = h - 1 + hh; int gw = w_base - 1 + pos;
            float vm = 0.f, vs = 0.f;
            if ((unsigned)gh < (unsigned)HH && (unsigned)gw < (unsigned)WW){
                long gi = ((long)(b*CIN + (c+ci_l))*HH + gh)*WW + gw;
                vm = mean[gi];
                float sv = stdv[gi];
                vs = sv*sv;
            }
            lds_m[ci_l][hh][pos] = vm;
            lds_s[ci_l][hh][pos] = vs;
        }
        __syncthreads();
        for (int ci_l=0; ci_l<CI_CHUNK; ++ci_l){
            int rbase = (c+ci_l)*9;
            #pragma unroll
            for (int kh=0; kh<3; ++kh){
                float w0 = wT[(long)(rbase + kh*3 + 0)*COUT + co];
                float w1 = wT[(long)(rbase + kh*3 + 1)*COUT + co];
                float w2 = wT[(long)(rbase + kh*3 + 2)*COUT + co];
                float xm[30];
                #pragma unroll
                for (int p=0;p<30;p++) xm[p] = lds_m[ci_l][kh][p];
                #pragma unroll
                for (int i=0;i<28;i++) acc_m[i] += w0*xm[i] + w1*xm[i+1] + w2*xm[i+2];
                float q0=w0*w0, q1=w1*w1, q2=w2*w2;
                float xs[30];
                #pragma unroll
                for (int p=0;p<30;p++) xs[p] = lds_s[ci_l][kh][p];
                #pragma unroll
                for (int i=0;i<28;i++) acc_v[i] += q0*xs[i] + q1*xs[i+1] + q2*xs[i+2];
            }
        }
        __syncthreads();
    }
    float bvv = bias[co];
    long obase = ((long)(b*COUT+co)*HH + h)*WW + w_base;
    #pragma unroll
    for (int i=0;i<28;i++){
        m_out[obase+i] = f2b(acc_m[i]+bvv);
        v_out[obase+i] = f2b(acc_v[i]);
    }
}

// ================= launcher =================
extern "C" void kernel_launch(void* const* d_in, const int* in_sizes, int n_in,
                              void* d_out, int out_size, void* d_ws, size_t ws_size,
                              hipStream_t stream)
{
    const float* mean   = (const float*)d_in[0];
    const float* stdv   = (const float*)d_in[1];
    const float* conv_w = (const float*)d_in[2];
    const float* conv_b = (const float*)d_in[3];
    const float* gamma  = (const float*)d_in[4];
    const float* beta   = (const float*)d_in[5];
    float* out = (float*)d_out;
    char* ws = (char*)d_ws;

    // fast-path workspace layout (bytes)
    const size_t PAD_BYTES  = (size_t)BB*PADH*PADW*CIN*2;        // 27,549,696
    const size_t OFF_STD2   = PAD_BYTES;
    const size_t OFF_WT     = 2*PAD_BYTES;                        // 55,099,392
    const size_t WT_BYTES   = (size_t)9*COUT*CIN*2;               // 589,824
    const size_t OFF_WT2    = OFF_WT + WT_BYTES;
    const size_t OFF_M      = OFF_WT2 + WT_BYTES;                 // 56,279,040
    const size_t MV_BYTES   = (size_t)BB*COUT*HW*2;               // 51,380,224
    const size_t OFF_V      = OFF_M + MV_BYTES;
    const size_t OFF_MU     = OFF_V + MV_BYTES;                   // 159,039,488
    const size_t OFF_INV    = OFF_MU + 1024;
    const size_t OFF_SUM    = OFF_INV + 1024;
    const size_t OFF_SUMSQ  = OFF_SUM + 1024;
    const size_t NEED_FAST  = OFF_SUMSQ + 1024;

    if (ws_size >= NEED_FAST){
        u16* mean_pad = (u16*)ws;
        u16* std2_pad = (u16*)(ws + OFF_STD2);
        u16* wT   = (u16*)(ws + OFF_WT);
        u16* wT2  = (u16*)(ws + OFF_WT2);
        u16* m_buf = (u16*)(ws + OFF_M);
        u16* v_buf = (u16*)(ws + OFF_V);
        float* mu  = (float*)(ws + OFF_MU);
        float* inv = (float*)(ws + OFF_INV);
        float* sum_   = (float*)(ws + OFF_SUM);
        float* sumsq_ = (float*)(ws + OFF_SUMSQ);

        hipMemsetAsync(ws + OFF_SUM, 0, 2048, stream);   // zero stats accumulators
        halo_kernel<<<(BB*228*16)/256, 256, 0, stream>>>(mean_pad, std2_pad);
        transform_kernel<<<(BB*HH*WW*16)/256, 256, 0, stream>>>(mean, stdv, mean_pad, std2_pad);
        wtransb_kernel<<<(9*COUT*CIN)/256, 256, 0, stream>>>(conv_w, wT, wT2);
        convs_kernel<<<dim3((NPIX/128)*(COUT/128), 1, 2), 256, 0, stream>>>(
            mean_pad, std2_pad, wT, wT2, conv_b, m_buf, v_buf, sum_, sumsq_);
        finalize_kernel<<<1, 256, 0, stream>>>(sum_, sumsq_, mu, inv);
        final_kernel<<<(int)(POOL_ELEMS/256), 256, 0, stream>>>(m_buf, v_buf, mu, inv, gamma, beta, out);
    } else {
        // fallback: round-2 structure with bf16 m/v
        u16* m_buf = (u16*)ws;
        u16* v_buf = (u16*)(ws + (size_t)BB*COUT*HW*2);
        float* wT  = (float*)(ws + (size_t)BB*COUT*HW*4);
        float* mu  = (float*)(ws + (size_t)BB*COUT*HW*4 + (size_t)COUT*CIN*9*4);
        float* inv = mu + 256;
        wtransf_kernel<<<(COUT*CIN*9+255)/256, 256, 0, stream>>>(conv_w, wT);
        conv_old_kernel<<<dim3(2, HH, BB), 256, 0, stream>>>(mean, stdv, wT, conv_b, m_buf, v_buf);
        stats_old_kernel<<<COUT, 256, 0, stream>>>(m_buf, mu, inv);
        final_kernel<<<(int)(POOL_ELEMS/256), 256, 0, stream>>>(m_buf, v_buf, mu, inv, gamma, beta, out);
    }
}

// Round 5
// 261.601 us; speedup vs baseline: 9.9712x; 1.0734x over previous
//
#include <hip/hip_runtime.h>
#include <hip/hip_bf16.h>
#include <math.h>

// ---------------- problem constants ----------------
#define BB 32
#define CIN 128
#define HH 56
#define WW 56
#define COUT 256
#define HW (HH*WW)              // 3136
#define NPIX (BB*HW)            // 100352
#define PH 28
#define PW 28
#define POOL_ELEMS ((long)BB*COUT*PH*PW) // 6,422,528
#define PADH 58
#define PADW 58

typedef unsigned short u16;
using s16x8 = __attribute__((ext_vector_type(8))) short;
using s16x4 = __attribute__((ext_vector_type(4))) short;
using f32x4 = __attribute__((ext_vector_type(4))) float;

__device__ __forceinline__ float b2f(u16 u){ return __uint_as_float(((unsigned)u)<<16); }
__device__ __forceinline__ u16 f2b(float x){           // RNE f32->bf16
    unsigned u = __float_as_uint(x);
    unsigned r = (u + 0x7fffu + ((u>>16)&1u)) >> 16;
    return (u16)r;
}

__device__ __forceinline__ void gload16(const void* g, void* l){
    __builtin_amdgcn_global_load_lds(
        (const __attribute__((address_space(1))) unsigned int*)g,
        (__attribute__((address_space(3))) unsigned int*)l, 16, 0, 0);
}

// ================= FAST PATH =================

// NCHW f32 -> padded NHWC bf16 (mean, std^2); halo positions write zeros (fused).
__global__ __launch_bounds__(256) void transform_kernel(
    const float* __restrict__ mean, const float* __restrict__ stdv,
    u16* __restrict__ mean_pad, u16* __restrict__ std2_pad)
{
    int t   = blockIdx.x*256 + threadIdx.x;   // exactly BB*PADH*PADW*16 threads
    int oct = t & 15;
    int pp  = t >> 4;                          // padded pixel: (b*PADH+ph)*PADW+pw
    int pw = pp % PADW; int tmp = pp / PADW;
    int ph = tmp % PADH; int b = tmp / PADH;
    size_t obase = (size_t)pp*CIN + oct*8;
    s16x8 pm = (s16x8){0,0,0,0,0,0,0,0}, ps = pm;
    if (ph >= 1 && ph <= HH && pw >= 1 && pw <= WW){
        long ibase = ((long)(b*CIN + oct*8)*HH + (ph-1))*WW + (pw-1);
        #pragma unroll
        for (int j=0;j<8;j++){
            float m = mean[ibase + (long)j*HW];
            float s = stdv[ibase + (long)j*HW];
            pm[j] = (short)f2b(m);
            ps[j] = (short)f2b(s*s);
        }
    }
    *(s16x8*)(mean_pad + obase) = pm;
    *(s16x8*)(std2_pad + obase) = ps;
}

// w[co][ci][3][3] f32 -> wT[r][co][ci] bf16 and squared copy
__global__ __launch_bounds__(256) void wtransb_kernel(
    const float* __restrict__ w, u16* __restrict__ wT, u16* __restrict__ wT2)
{
    int t = blockIdx.x*256 + threadIdx.x;   // exactly 294912
    int ci = t & 127;
    int co = (t>>7) & 255;
    int r  = t >> 15;                        // 0..8
    float v = w[((long)co*CIN + ci)*9 + r];
    long o = ((long)r*COUT + co)*CIN + ci;
    wT[o]  = f2b(v);
    wT2[o] = f2b(v*v);
}

// implicit-GEMM conv via MFMA. blockIdx.z: 0 = mean*w (+bias,+stats), 1 = std2*w2.
// Tiles: BM=128 pixels, BN=128 co, BK=64 ci (18 k-steps => half the barrier drains
// vs BK=32). 4 waves (2x2), each wave 64x64, 4x4 frags of 16x16x32.
// LDS tile [128 rows][64 ci] bf16: row stride 128B => XOR-swizzle the 16B-slot
// index with (row&7); linear LDS dest + pre-swizzled GLOBAL source + swizzled read.
__global__ __launch_bounds__(256,4) void convs_kernel(
    const u16* __restrict__ mean_pad, const u16* __restrict__ std2_pad,
    const u16* __restrict__ wT, const u16* __restrict__ wT2,
    const float* __restrict__ bias,
    u16* __restrict__ m_out, u16* __restrict__ v_out,
    float* __restrict__ sum_, float* __restrict__ sumsq_)
{
    __shared__ u16 ldsA[8192];   // 16KB
    __shared__ u16 ldsB[8192];   // 16KB
    const int tid  = threadIdx.x;
    const int lane = tid & 63;
    const int wid  = tid >> 6;
    const int wm   = wid >> 1, wn = wid & 1;
    const int path = blockIdx.z;

    const u16* __restrict__ Ap = path ? std2_pad : mean_pad;
    const u16* __restrict__ Bp = path ? wT2      : wT;
    u16*       __restrict__ Op = path ? v_out    : m_out;

    // XCD-bijective swizzle: 1568 blocks in x, 1568/8 = 196
    int bid = blockIdx.x;
    int swz = (bid & 7) * 196 + (bid >> 3);
    const int pix0 = (swz >> 1) * 128;
    const int co0  = (swz & 1) * 128;

    // staging: issue i (0..3) of wave wid writes LDS slots s = (i*4+wid)*64 + lane;
    // row = s>>3 = (i*4+wid)*8 + (lane>>3), slot-in-row = lane&7.
    // source oct is pre-swizzled: oct_src = (lane&7) ^ (row&7), and row&7 == lane>>3.
    const int oct_src = (lane & 7) ^ (lane >> 3);
    size_t aoff[4];
    #pragma unroll
    for (int i=0;i<4;i++){
        int row = (i*4 + wid)*8 + (lane>>3);
        int gp = pix0 + row;
        int b = gp / HW; int rem = gp % HW;
        int h = rem / WW; int w = rem % WW;
        aoff[i] = (((size_t)b*PADH + h)*PADW + w)*CIN + (size_t)oct_src*8;
    }
    const int row0 = wid*8 + (lane>>3);
    size_t boff0 = ((size_t)(co0 + row0))*CIN + (size_t)oct_src*8;

    // fragment read offsets (u16 index in [128][64] tile), same XOR on read.
    // kk=1 toggles slot bit2 => u16-index XOR 32.
    int a_idx[4], b_idx[4];
    #pragma unroll
    for (int t4=0;t4<4;t4++){
        int row  = wm*64 + t4*16 + (lane & 15);
        a_idx[t4] = row*64 + (((lane>>4) ^ (row&7))*8);
        int crow = wn*64 + t4*16 + (lane & 15);
        b_idx[t4] = crow*64 + (((lane>>4) ^ (crow&7))*8);
    }

    f32x4 acc[4][4];
    #pragma unroll
    for (int i=0;i<4;i++)
      #pragma unroll
      for (int j=0;j<4;j++) acc[i][j] = (f32x4){0.f,0.f,0.f,0.f};

    for (int r=0; r<9; ++r){
        const size_t ash = (size_t)((r/3)*PADW + (r%3))*CIN;
        const size_t wsh = (size_t)r*COUT*CIN;
        #pragma unroll
        for (int cs=0; cs<2; ++cs){
            const size_t ao = ash + (size_t)cs*64;
            const size_t wo = wsh + (size_t)cs*64;
            __syncthreads();   // all waves done reading LDS from previous k-step
            gload16(Ap + aoff[0] + ao, &ldsA[(0*4+wid)*512]);
            gload16(Ap + aoff[1] + ao, &ldsA[(1*4+wid)*512]);
            gload16(Ap + aoff[2] + ao, &ldsA[(2*4+wid)*512]);
            gload16(Ap + aoff[3] + ao, &ldsA[(3*4+wid)*512]);
            gload16(Bp + boff0 + 0*32*CIN + wo, &ldsB[(0*4+wid)*512]);
            gload16(Bp + boff0 + 1*32*CIN + wo, &ldsB[(1*4+wid)*512]);
            gload16(Bp + boff0 + 2*32*CIN + wo, &ldsB[(2*4+wid)*512]);
            gload16(Bp + boff0 + 3*32*CIN + wo, &ldsB[(3*4+wid)*512]);
            __syncthreads();   // vmcnt(0) drained before barrier -> LDS ready

            #pragma unroll
            for (int kk=0; kk<2; ++kk){
                const int kx = kk*32;
                s16x8 af[4], bfg[4];
                #pragma unroll
                for (int t4=0;t4<4;t4++) af[t4]  = *(const s16x8*)&ldsA[a_idx[t4] ^ kx];
                #pragma unroll
                for (int t4=0;t4<4;t4++) bfg[t4] = *(const s16x8*)&ldsB[b_idx[t4] ^ kx];
                #pragma unroll
                for (int mi=0;mi<4;mi++)
                  #pragma unroll
                  for (int ni=0;ni<4;ni++)
                    acc[mi][ni] = __builtin_amdgcn_mfma_f32_16x16x32_bf16(af[mi], bfg[ni], acc[mi][ni], 0,0,0);
            }
        }
    }

    // epilogue. D-frag: col=lane&15, row=(lane>>4)*4+reg.
    float bv[4];
    if (path == 0){
        #pragma unroll
        for (int ni=0;ni<4;ni++) bv[ni] = bias[co0 + wn*64 + ni*16 + (lane&15)];
    } else {
        #pragma unroll
        for (int ni=0;ni<4;ni++) bv[ni] = 0.f;
    }

    float ssum[4], ssq[4];
    #pragma unroll
    for (int ni=0;ni<4;ni++){ ssum[ni]=0.f; ssq[ni]=0.f; }

    #pragma unroll
    for (int mi=0;mi<4;mi++){
        int pixl = wm*64 + mi*16 + ((lane>>4)<<2);
        int gp = pix0 + pixl;
        int b = gp / HW; int hw = gp - b*HW;   // 4 consecutive pix stay in same (b,h) row
        #pragma unroll
        for (int ni=0;ni<4;ni++){
            int co = co0 + wn*64 + ni*16 + (lane&15);
            size_t o = (size_t)(b*COUT + co)*HW + hw;
            s16x4 pk;
            #pragma unroll
            for (int rr=0;rr<4;rr++){
                float v = acc[mi][ni][rr] + bv[ni];
                pk[rr] = (short)f2b(v);
                ssum[ni] += v;
                ssq[ni]  += v*v;
            }
            *(s16x4*)(Op + o) = pk;
        }
    }

    if (path == 0){
        // reduce over the 4 lane-groups sharing (lane&15) => per-co partials
        #pragma unroll
        for (int ni=0;ni<4;ni++){
            float s = ssum[ni], s2 = ssq[ni];
            s  += __shfl_xor(s, 16, 64);  s2 += __shfl_xor(s2, 16, 64);
            s  += __shfl_xor(s, 32, 64);  s2 += __shfl_xor(s2, 32, 64);
            if (lane < 16){
                int co = co0 + wn*64 + ni*16 + lane;
                atomicAdd(&sum_[co],   s);
                atomicAdd(&sumsq_[co], s2);
            }
        }
    }
}

// 1 block: per-channel mu / inv-std from atomic partials
__global__ __launch_bounds__(256) void finalize_kernel(
    const float* __restrict__ sum_, const float* __restrict__ sumsq_,
    float* __restrict__ mu_out, float* __restrict__ inv_out)
{
    int co = threadIdx.x;
    float mu = sum_[co] / (float)NPIX;
    float var = sumsq_[co] / (float)NPIX - mu*mu;
    mu_out[co] = mu;
    inv_out[co] = 1.0f/sqrtf(var + 1e-5f);
}

// BN + erf + 2x2 pool -> f32 outputs; 4 pooled outputs per thread (16B loads/stores)
__global__ __launch_bounds__(256) void final_kernel(
        const u16* __restrict__ m, const u16* __restrict__ var,
        const float* __restrict__ mu_, const float* __restrict__ inv_,
        const float* __restrict__ gamma, const float* __restrict__ beta,
        float* __restrict__ out){
    int idx4 = blockIdx.x*256 + threadIdx.x;   // < POOL_ELEMS/4
    int wo4 = idx4 % (PW/4); int t = idx4 / (PW/4);
    int ho = t % PH; t /= PH;
    int co = t % COUT; int b = t / COUT;
    float g  = gamma[co];
    float be = beta[co];
    float mu = mu_[co], inv = inv_[co];
    float ag = fabsf(g);
    float us[4] = {0.f,0.f,0.f,0.f}, ss[4] = {0.f,0.f,0.f,0.f};
    #pragma unroll
    for (int dh=0; dh<2; ++dh){
        long base = ((long)(b*COUT+co)*HH + 2*ho+dh)*WW + wo4*8;
        const s16x8 vm = *(const s16x8*)&m[base];
        const s16x8 vv = *(const s16x8*)&var[base];
        #pragma unroll
        for (int j=0;j<8;j++){
            float mm = b2f((u16)vm[j]);
            float sdev = sqrtf(b2f((u16)vv[j]) + 1e-12f);
            float uhat = (mm - mu)*inv*g + be;
            float shat = sdev*inv*ag;
            float z = uhat / (shat*1.41421356237f + 1e-12f);
            float u = 0.5f*(1.f + erff(z));
            us[j>>1] += u;
            ss[j>>1] += fmaxf(u*(1.f-u), 1e-12f);
        }
    }
    long ob = ((long)(b*COUT+co)*PH + ho)*PW + wo4*4;
    f32x4 o0, o1;
    #pragma unroll
    for (int k=0;k<4;k++){
        o0[k] = 0.25f*us[k];
        o1[k] = sqrtf(0.25f*ss[k])*0.5f;
    }
    *(f32x4*)(out + ob) = o0;
    *(f32x4*)(out + POOL_ELEMS + ob) = o1;
}

// ================= FALLBACK PATH (round-2 VALU conv, bf16 m/v out) =================

__global__ void wtransf_kernel(const float* __restrict__ w, float* __restrict__ wT){
    int out = blockIdx.x*256 + threadIdx.x;
    if (out >= COUT*CIN*9) return;
    int co = out % COUT;
    int r  = out / COUT;
    wT[out] = w[(long)co*(CIN*9) + r];
}

__global__ __launch_bounds__(256) void stats_old_kernel(const u16* __restrict__ m,
        float* __restrict__ mu_out, float* __restrict__ inv_out){
    int co = blockIdx.x;
    float s=0.f, s2=0.f;
    for (int oc = threadIdx.x; oc < NPIX/8; oc += 256){
        int b = oc / (HW/8); int o8 = oc - b*(HW/8);
        const s16x8 v8 = *(const s16x8*)&m[((size_t)(b*COUT+co))*HW + (size_t)o8*8];
        #pragma unroll
        for (int j=0;j<8;j++){ float v = b2f((u16)v8[j]); s += v; s2 += v*v; }
    }
    __shared__ float rs[256], rs2[256];
    rs[threadIdx.x]=s; rs2[threadIdx.x]=s2; __syncthreads();
    for (int o=128;o>0;o>>=1){
        if (threadIdx.x < o){ rs[threadIdx.x]+=rs[threadIdx.x+o]; rs2[threadIdx.x]+=rs2[threadIdx.x+o]; }
        __syncthreads();
    }
    if (threadIdx.x==0){
        float mu = rs[0]/(float)NPIX;
        float var = rs2[0]/(float)NPIX - mu*mu;
        mu_out[co] = mu;
        inv_out[co] = 1.0f/sqrtf(var + 1e-5f);
    }
}

__global__ __launch_bounds__(256) void final_old_kernel(
        const u16* __restrict__ m, const u16* __restrict__ var,
        const float* __restrict__ mu_, const float* __restrict__ inv_,
        const float* __restrict__ gamma, const float* __restrict__ beta,
        float* __restrict__ out){
    long idx = (long)blockIdx.x*256 + threadIdx.x;
    int wo = (int)(idx % PW); long t = idx / PW;
    int ho = (int)(t % PH); t /= PH;
    int co = (int)(t % COUT); int b = (int)(t / COUT);
    float g  = gamma[co];
    float be = beta[co];
    float mu = mu_[co], inv = inv_[co];
    float ag = fabsf(g);
    float us = 0.f, ss = 0.f;
    #pragma unroll
    for (int dh=0; dh<2; ++dh){
        int hpos = 2*ho+dh;
        long base = ((long)(b*COUT+co)*HH + hpos)*WW + 2*wo;
        #pragma unroll
        for (int dw=0; dw<2; ++dw){
            float mm = b2f(m[base+dw]);
            float vv = b2f(var[base+dw]);
            float sdev = sqrtf(vv + 1e-12f);
            float uhat = (mm - mu)*inv*g + be;
            float shat = sdev*inv*ag;
            float z = uhat / (shat*1.41421356237f + 1e-12f);
            float u = 0.5f*(1.f + erff(z));
            float sa2 = fmaxf(u*(1.f-u), 1e-12f);
            us += u; ss += sa2;
        }
    }
    out[idx]              = 0.25f*us;
    out[POOL_ELEMS + idx] = sqrtf(0.25f*ss)*0.5f;
}

#define CI_CHUNK 64
#define XW 32
__global__ __launch_bounds__(256) void conv_old_kernel(
    const float* __restrict__ mean, const float* __restrict__ stdv,
    const float* __restrict__ wT, const float* __restrict__ bias,
    u16* __restrict__ m_out, u16* __restrict__ v_out)
{
    __shared__ float lds_m[CI_CHUNK][3][XW];
    __shared__ float lds_s[CI_CHUNK][3][XW];
    const int co   = threadIdx.x;
    const int half = blockIdx.x;
    const int h    = blockIdx.y;
    const int b    = blockIdx.z;
    const int w_base = half*28;

    float acc_m[28], acc_v[28];
    #pragma unroll
    for (int i=0;i<28;i++){ acc_m[i]=0.f; acc_v[i]=0.f; }

    for (int c=0; c<CIN; c+=CI_CHUNK){
        for (int t = threadIdx.x; t < CI_CHUNK*3*30; t += 256){
            int pos = t % 30; int r = t / 30; int hh = r % 3; int ci_l = r / 3;
            int gh = h - 1 + hh; int gw = w_base - 1 + pos;
            float vm = 0.f, vs = 0.f;
            if ((unsigned)gh < (unsigned)HH && (unsigned)gw < (unsigned)WW){
                long gi = ((long)(b*CIN + (c+ci_l))*HH + gh)*WW + gw;
                vm = mean[gi];
                float sv = stdv[gi];
                vs = sv*sv;
            }
            lds_m[ci_l][hh][pos] = vm;
            lds_s[ci_l][hh][pos] = vs;
        }
        __syncthreads();
        for (int ci_l=0; ci_l<CI_CHUNK; ++ci_l){
            int rbase = (c+ci_l)*9;
            #pragma unroll
            for (int kh=0; kh<3; ++kh){
                float w0 = wT[(long)(rbase + kh*3 + 0)*COUT + co];
                float w1 = wT[(long)(rbase + kh*3 + 1)*COUT + co];
                float w2 = wT[(long)(rbase + kh*3 + 2)*COUT + co];
                float xm[30];
                #pragma unroll
                for (int p=0;p<30;p++) xm[p] = lds_m[ci_l][kh][p];
                #pragma unroll
                for (int i=0;i<28;i++) acc_m[i] += w0*xm[i] + w1*xm[i+1] + w2*xm[i+2];
                float q0=w0*w0, q1=w1*w1, q2=w2*w2;
                float xs[30];
                #pragma unroll
                for (int p=0;p<30;p++) xs[p] = lds_s[ci_l][kh][p];
                #pragma unroll
                for (int i=0;i<28;i++) acc_v[i] += q0*xs[i] + q1*xs[i+1] + q2*xs[i+2];
            }
        }
        __syncthreads();
    }
    float bvv = bias[co];
    long obase = ((long)(b*COUT+co)*HH + h)*WW + w_base;
    #pragma unroll
    for (int i=0;i<28;i++){
        m_out[obase+i] = f2b(acc_m[i]+bvv);
        v_out[obase+i] = f2b(acc_v[i]);
    }
}

// ================= launcher =================
extern "C" void kernel_launch(void* const* d_in, const int* in_sizes, int n_in,
                              void* d_out, int out_size, void* d_ws, size_t ws_size,
                              hipStream_t stream)
{
    const float* mean   = (const float*)d_in[0];
    const float* stdv   = (const float*)d_in[1];
    const float* conv_w = (const float*)d_in[2];
    const float* conv_b = (const float*)d_in[3];
    const float* gamma  = (const float*)d_in[4];
    const float* beta   = (const float*)d_in[5];
    float* out = (float*)d_out;
    char* ws = (char*)d_ws;

    // fast-path workspace layout (bytes)
    const size_t PAD_BYTES  = (size_t)BB*PADH*PADW*CIN*2;        // 27,549,696
    const size_t OFF_STD2   = PAD_BYTES;
    const size_t OFF_WT     = 2*PAD_BYTES;                        // 55,099,392
    const size_t WT_BYTES   = (size_t)9*COUT*CIN*2;               // 589,824
    const size_t OFF_WT2    = OFF_WT + WT_BYTES;
    const size_t OFF_M      = OFF_WT2 + WT_BYTES;                 // 56,279,040
    const size_t MV_BYTES   = (size_t)BB*COUT*HW*2;               // 51,380,224
    const size_t OFF_V      = OFF_M + MV_BYTES;
    const size_t OFF_MU     = OFF_V + MV_BYTES;                   // 159,039,488
    const size_t OFF_INV    = OFF_MU + 1024;
    const size_t OFF_SUM    = OFF_INV + 1024;
    const size_t OFF_SUMSQ  = OFF_SUM + 1024;
    const size_t NEED_FAST  = OFF_SUMSQ + 1024;

    if (ws_size >= NEED_FAST){
        u16* mean_pad = (u16*)ws;
        u16* std2_pad = (u16*)(ws + OFF_STD2);
        u16* wT   = (u16*)(ws + OFF_WT);
        u16* wT2  = (u16*)(ws + OFF_WT2);
        u16* m_buf = (u16*)(ws + OFF_M);
        u16* v_buf = (u16*)(ws + OFF_V);
        float* mu  = (float*)(ws + OFF_MU);
        float* inv = (float*)(ws + OFF_INV);
        float* sum_   = (float*)(ws + OFF_SUM);
        float* sumsq_ = (float*)(ws + OFF_SUMSQ);

        hipMemsetAsync(ws + OFF_SUM, 0, 2048, stream);   // zero stats accumulators
        transform_kernel<<<(BB*PADH*PADW*16)/256, 256, 0, stream>>>(mean, stdv, mean_pad, std2_pad);
        wtransb_kernel<<<(9*COUT*CIN)/256, 256, 0, stream>>>(conv_w, wT, wT2);
        convs_kernel<<<dim3((NPIX/128)*(COUT/128), 1, 2), 256, 0, stream>>>(
            mean_pad, std2_pad, wT, wT2, conv_b, m_buf, v_buf, sum_, sumsq_);
        finalize_kernel<<<1, 256, 0, stream>>>(sum_, sumsq_, mu, inv);
        final_kernel<<<(int)(POOL_ELEMS/4/256), 256, 0, stream>>>(m_buf, v_buf, mu, inv, gamma, beta, out);
    } else {
        // fallback: round-2 structure with bf16 m/v
        u16* m_buf = (u16*)ws;
        u16* v_buf = (u16*)(ws + (size_t)BB*COUT*HW*2);
        float* wT  = (float*)(ws + (size_t)BB*COUT*HW*4);
        float* mu  = (float*)(ws + (size_t)BB*COUT*HW*4 + (size_t)COUT*CIN*9*4);
        float* inv = mu + 256;
        wtransf_kernel<<<(COUT*CIN*9+255)/256, 256, 0, stream>>>(conv_w, wT);
        conv_old_kernel<<<dim3(2, HH, BB), 256, 0, stream>>>(mean, stdv, wT, conv_b, m_buf, v_buf);
        stats_old_kernel<<<COUT, 256, 0, stream>>>(m_buf, mu, inv);
        final_old_kernel<<<(int)(POOL_ELEMS/256), 256, 0, stream>>>(m_buf, v_buf, mu, inv, gamma, beta, out);
    }
}